// Round 1
// 1594.461 us; speedup vs baseline: 1.3243x; 1.3243x over previous
//
#include <hip/hip_runtime.h>
#include <cstdint>

constexpr int Nn = 20000;
constexpr int Ee = 320000;   // Nn * 16
constexpr int KN = 6;

// ---------------------------------------------------------------------------
// feast1: scatter-add x[src] into agg16[dst], count in-degree
// ---------------------------------------------------------------------------
__global__ __launch_bounds__(256) void scatter16(const float* __restrict__ x,
                                                 const int* __restrict__ ei,
                                                 float* __restrict__ agg,
                                                 int* __restrict__ cnt) {
  int tid = blockIdx.x * 256 + threadIdx.x;
  int e = tid >> 4, c = tid & 15;
  if (e >= Ee) return;
  int s = ei[e], d = ei[Ee + e];
  unsafeAtomicAdd(&agg[d * 16 + c], x[s * 16 + c]);
  if (c == 0) atomicAdd(&cnt[d], 1);
}

// feast1 finalize: x1 = relu(((agg + x)/ (cnt+1)) @ cW1 + cb1); sq = ||x1||^2
__global__ __launch_bounds__(256) void feast1_fin(const float* __restrict__ x,
                                                  const float* __restrict__ agg,
                                                  const int* __restrict__ cnt,
                                                  const float* __restrict__ W,
                                                  const float* __restrict__ b,
                                                  float* __restrict__ x1,
                                                  float* __restrict__ sq) {
  __shared__ float sW[256];
  __shared__ float sb[16];
  sW[threadIdx.x] = W[threadIdx.x];
  if (threadIdx.x < 16) sb[threadIdx.x] = b[threadIdx.x];
  __syncthreads();
  int n = blockIdx.x * 256 + threadIdx.x;
  if (n >= Nn) return;
  float inv = 1.0f / (float)(cnt[n] + 1);
  float v[16];
#pragma unroll
  for (int c = 0; c < 16; ++c) v[c] = (agg[n * 16 + c] + x[n * 16 + c]) * inv;
  float s = 0.0f;
#pragma unroll
  for (int o = 0; o < 16; ++o) {
    float a = sb[o];
#pragma unroll
    for (int c = 0; c < 16; ++c) a = fmaf(v[c], sW[c * 16 + o], a);
    a = fmaxf(a, 0.0f);
    x1[n * 16 + o] = a;
    s = fmaf(a, a, s);
  }
  sq[n] = s;
}

// ---------------------------------------------------------------------------
// kNN: partial top-6 per (row, column-chunk). xj loaded with wave-uniform j
// (compiler emits s_load + SGPR-broadcast FMA). R rows per thread in VGPRs.
// Selection key: ||xj||^2 - 2 xi.xj  (row-constant ||xi||^2 dropped).
// Occupancy note: grid = grid.x * P blocks; sized so >=16 waves/CU resident
// (previous R=4/P=16 config gave only ~5 waves/CU -> VALUBusy 35%).
// ---------------------------------------------------------------------------
template <int C, int R, int TPB>
__global__ __launch_bounds__(TPB) void knn_part(const float* __restrict__ xf,
                                                const float* __restrict__ sq,
                                                float* __restrict__ pd,
                                                int* __restrict__ pi, int chunk) {
  const int rowsPerBlock = TPB * R;
  const int row0 = blockIdx.x * rowsPerBlock;
  const int p = blockIdx.y;
  const int j0 = p * chunk;
  int j1 = j0 + chunk;
  if (j1 > Nn) j1 = Nn;

  float xi[R][C];
  int rowv[R];
#pragma unroll
  for (int r = 0; r < R; ++r) {
    int row = row0 + (int)threadIdx.x + r * TPB;
    rowv[r] = row;
    const float* src = xf + (size_t)(row < Nn ? row : 0) * C;
#pragma unroll
    for (int c = 0; c < C; ++c) xi[r][c] = src[c];
  }
  float bd[R][KN];
  int bi[R][KN];
#pragma unroll
  for (int r = 0; r < R; ++r)
#pragma unroll
    for (int k = 0; k < KN; ++k) { bd[r][k] = __builtin_inff(); bi[r][k] = -1; }

#pragma unroll 2
  for (int j = j0; j < j1; ++j) {
    const float* xjp = xf + (size_t)j * C;  // uniform address -> scalar loads
    float sqj = sq[j];
    float xj[C];
#pragma unroll
    for (int c = 0; c < C; ++c) xj[c] = xjp[c];
    float s[R];
#pragma unroll
    for (int r = 0; r < R; ++r) {
      float acc = 0.0f;
#pragma unroll
      for (int c = 0; c < C; ++c) acc = fmaf(xi[r][c], xj[c], acc);
      float d = fmaf(-2.0f, acc, sqj);
      s[r] = (j == rowv[r]) ? __builtin_inff() : d;
    }
    bool any = false;
#pragma unroll
    for (int r = 0; r < R; ++r) any = any || (s[r] < bd[r][KN - 1]);
    if (__builtin_expect(any, 0)) {
#pragma unroll
      for (int r = 0; r < R; ++r) {
        if (s[r] < bd[r][KN - 1]) {
          bd[r][KN - 1] = s[r];
          bi[r][KN - 1] = j;
#pragma unroll
          for (int k = KN - 1; k >= 1; --k) {
            if (bd[r][k] < bd[r][k - 1]) {
              float td = bd[r][k]; bd[r][k] = bd[r][k - 1]; bd[r][k - 1] = td;
              int ti = bi[r][k]; bi[r][k] = bi[r][k - 1]; bi[r][k - 1] = ti;
            }
          }
        }
      }
    }
  }
#pragma unroll
  for (int r = 0; r < R; ++r) {
    if (rowv[r] < Nn) {
      size_t base = ((size_t)p * Nn + rowv[r]) * KN;
      for (int k = 0; k < KN; ++k) { pd[base + k] = bd[r][k]; pi[base + k] = bi[r][k]; }
    }
  }
}

// merge P partial top-6 lists (stable: ascending p == ascending j ranges)
__global__ __launch_bounds__(256) void knn_merge(const float* __restrict__ pd,
                                                 const int* __restrict__ pi,
                                                 int* __restrict__ idx, int P) {
  int row = blockIdx.x * 256 + threadIdx.x;
  if (row >= Nn) return;
  float bd[KN];
  int bi[KN];
#pragma unroll
  for (int k = 0; k < KN; ++k) { bd[k] = __builtin_inff(); bi[k] = -1; }
  for (int p = 0; p < P; ++p) {
    size_t base = ((size_t)p * Nn + row) * KN;
#pragma unroll
    for (int k = 0; k < KN; ++k) {
      float d = pd[base + k];
      int id = pi[base + k];
      if (d < bd[KN - 1]) {
        bd[KN - 1] = d; bi[KN - 1] = id;
#pragma unroll
        for (int m = KN - 1; m >= 1; --m) {
          if (bd[m] < bd[m - 1]) {
            float td = bd[m]; bd[m] = bd[m - 1]; bd[m - 1] = td;
            int ti = bi[m]; bi[m] = bi[m - 1]; bi[m - 1] = ti;
          }
        }
      }
    }
  }
  for (int k = 0; k < KN; ++k) idx[row * KN + k] = bi[k];
}

// ---------------------------------------------------------------------------
// EdgeConv MLP 1: in 16 -> tmp 32 -> hidden 32 -> out 32, max over 6 nbrs,
// y1 = relu(max), also sq2 = ||y1||^2. 8 nodes/block, 32 threads/node.
// ---------------------------------------------------------------------------
__global__ __launch_bounds__(256) void edge_mlp1(const float* __restrict__ xin,
                                                 const int* __restrict__ idx,
                                                 const float* __restrict__ W1,
                                                 const float* __restrict__ b1,
                                                 const float* __restrict__ W2,
                                                 const float* __restrict__ b2,
                                                 float* __restrict__ yout,
                                                 float* __restrict__ sqout) {
  __shared__ float sW1[1024], sW2[1024], sb1[32], sb2[32];
  __shared__ float xv[8][16], tmp[8][32], hv[8][32];
  int t = threadIdx.x & 31, g = threadIdx.x >> 5;
  for (int i = threadIdx.x; i < 1024; i += 256) { sW1[i] = W1[i]; sW2[i] = W2[i]; }
  if (threadIdx.x < 32) { sb1[threadIdx.x] = b1[threadIdx.x]; sb2[threadIdx.x] = b2[threadIdx.x]; }
  int node = blockIdx.x * 8 + g;
  bool valid = node < Nn;
  int nn = valid ? node : 0;
  if (t < 16) { float v = xin[nn * 16 + t]; xv[g][t] = v; tmp[g][t] = v; }
  __syncthreads();
  float acc = -__builtin_inff();
  for (int k = 0; k < KN; ++k) {
    int j = idx[nn * KN + k];
    if (t < 16) tmp[g][16 + t] = xin[j * 16 + t] - xv[g][t];
    __syncthreads();
    float h = sb1[t];
#pragma unroll
    for (int c = 0; c < 32; ++c) h = fmaf(tmp[g][c], sW1[c * 32 + t], h);
    h = fmaxf(h, 0.0f);
    hv[g][t] = h;
    __syncthreads();
    float o = sb2[t];
#pragma unroll
    for (int c = 0; c < 32; ++c) o = fmaf(hv[g][c], sW2[c * 32 + t], o);
    acc = fmaxf(acc, o);
  }
  float yv = fmaxf(acc, 0.0f);
  if (valid) yout[node * 32 + t] = yv;
  float s = yv * yv;
  s += __shfl_xor(s, 16, 32);
  s += __shfl_xor(s, 8, 32);
  s += __shfl_xor(s, 4, 32);
  s += __shfl_xor(s, 2, 32);
  s += __shfl_xor(s, 1, 32);
  if (valid && t == 0) sqout[node] = s;
}

// EdgeConv MLP 2: in 32 -> tmp 64 -> hidden 32 -> out 32, y2 = relu(max)
__global__ __launch_bounds__(256) void edge_mlp2(const float* __restrict__ yin,
                                                 const int* __restrict__ idx,
                                                 const float* __restrict__ W1,
                                                 const float* __restrict__ b1,
                                                 const float* __restrict__ W2,
                                                 const float* __restrict__ b2,
                                                 float* __restrict__ yout) {
  __shared__ float sW1[2048], sW2[1024], sb1[32], sb2[32];
  __shared__ float xv[8][32], tmp[8][64], hv[8][32];
  int t = threadIdx.x & 31, g = threadIdx.x >> 5;
  for (int i = threadIdx.x; i < 2048; i += 256) sW1[i] = W1[i];
  for (int i = threadIdx.x; i < 1024; i += 256) sW2[i] = W2[i];
  if (threadIdx.x < 32) { sb1[threadIdx.x] = b1[threadIdx.x]; sb2[threadIdx.x] = b2[threadIdx.x]; }
  int node = blockIdx.x * 8 + g;
  bool valid = node < Nn;
  int nn = valid ? node : 0;
  { float v = yin[nn * 32 + t]; xv[g][t] = v; tmp[g][t] = v; }
  __syncthreads();
  float acc = -__builtin_inff();
  for (int k = 0; k < KN; ++k) {
    int j = idx[nn * KN + k];
    tmp[g][32 + t] = yin[j * 32 + t] - xv[g][t];
    __syncthreads();
    float h = sb1[t];
#pragma unroll
    for (int c = 0; c < 64; ++c) h = fmaf(tmp[g][c], sW1[c * 32 + t], h);
    h = fmaxf(h, 0.0f);
    hv[g][t] = h;
    __syncthreads();
    float o = sb2[t];
#pragma unroll
    for (int c = 0; c < 32; ++c) o = fmaf(hv[g][c], sW2[c * 32 + t], o);
    acc = fmaxf(acc, o);
  }
  if (valid) yout[node * 32 + t] = fmaxf(acc, 0.0f);
}

// ---------------------------------------------------------------------------
// feast3: scatter cat0 = [x1, y1] (48) into agg48[dst]; reuse cnt from feast1
// ---------------------------------------------------------------------------
__global__ __launch_bounds__(256) void scatter48(const float* __restrict__ x1,
                                                 const float* __restrict__ y1,
                                                 const int* __restrict__ ei,
                                                 float* __restrict__ agg) {
  int tid = blockIdx.x * 256 + threadIdx.x;
  int e = tid / 48, c = tid - e * 48;
  if (e >= Ee) return;
  int s = ei[e], d = ei[Ee + e];
  float v = (c < 16) ? x1[s * 16 + c] : y1[s * 32 + (c - 16)];
  unsafeAtomicAdd(&agg[d * 48 + c], v);
}

// feast3 finalize: x3 = relu(((agg48 + cat0)/(cnt+1)) @ cW3 + cb3)
__global__ __launch_bounds__(256) void feast3_fin(const float* __restrict__ x1,
                                                  const float* __restrict__ y1,
                                                  const float* __restrict__ agg,
                                                  const int* __restrict__ cnt,
                                                  const float* __restrict__ W,
                                                  const float* __restrict__ b,
                                                  float* __restrict__ x3) {
  __shared__ float sW[3072];
  __shared__ float sb[64];
  for (int i = threadIdx.x; i < 3072; i += 256) sW[i] = W[i];
  if (threadIdx.x < 64) sb[threadIdx.x] = b[threadIdx.x];
  __syncthreads();
  int n = blockIdx.x * 256 + threadIdx.x;
  if (n >= Nn) return;
  float inv = 1.0f / (float)(cnt[n] + 1);
  float v[48];
#pragma unroll
  for (int c = 0; c < 16; ++c) v[c] = (agg[n * 48 + c] + x1[n * 16 + c]) * inv;
#pragma unroll
  for (int c = 16; c < 48; ++c) v[c] = (agg[n * 48 + c] + y1[n * 32 + (c - 16)]) * inv;
  for (int o = 0; o < 64; ++o) {
    float a = sb[o];
#pragma unroll
    for (int c = 0; c < 48; ++c) a = fmaf(v[c], sW[c * 64 + o], a);
    x3[n * 64 + o] = fmaxf(a, 0.0f);
  }
}

// ---------------------------------------------------------------------------
// Fused final MLP: cat1=[x3,y2](96) -> 96 -> 32 -> 8 -> sigmoid(1)
// 2 nodes/block, 128 threads/node; weights stream from L1/L2.
// ---------------------------------------------------------------------------
__global__ __launch_bounds__(256) void final_mlp(const float* __restrict__ x3,
                                                 const float* __restrict__ y2,
                                                 const float* __restrict__ l1W,
                                                 const float* __restrict__ l1b,
                                                 const float* __restrict__ l2W,
                                                 const float* __restrict__ l2b,
                                                 const float* __restrict__ l3W,
                                                 const float* __restrict__ l3b,
                                                 const float* __restrict__ oW,
                                                 const float* __restrict__ ob,
                                                 float* __restrict__ out) {
  __shared__ float cat[2][96], h1[2][96], h2[2][32], h3[2][8];
  int g = threadIdx.x >> 7, t = threadIdx.x & 127;
  int node = blockIdx.x * 2 + g;
  bool valid = node < Nn;
  int nn = valid ? node : 0;
  if (t < 96) cat[g][t] = (t < 64) ? x3[nn * 64 + t] : y2[nn * 32 + (t - 64)];
  __syncthreads();
  if (t < 96) {
    float a = l1b[t];
#pragma unroll
    for (int c = 0; c < 96; ++c) a = fmaf(cat[g][c], l1W[c * 96 + t], a);
    h1[g][t] = fmaxf(a, 0.0f);
  }
  __syncthreads();
  if (t < 32) {
    float a = l2b[t];
#pragma unroll
    for (int c = 0; c < 96; ++c) a = fmaf(h1[g][c], l2W[c * 32 + t], a);
    h2[g][t] = fmaxf(a, 0.0f);
  }
  __syncthreads();
  if (t < 8) {
    float a = l3b[t];
#pragma unroll
    for (int c = 0; c < 32; ++c) a = fmaf(h2[g][c], l3W[c * 8 + t], a);
    h3[g][t] = fmaxf(a, 0.0f);
  }
  __syncthreads();
  if (t == 0 && valid) {
    float a = ob[0];
#pragma unroll
    for (int c = 0; c < 8; ++c) a = fmaf(h3[g][c], oW[c], a);
    out[node] = 1.0f / (1.0f + expf(-a));
  }
}

// ---------------------------------------------------------------------------
extern "C" void kernel_launch(void* const* d_in, const int* in_sizes, int n_in,
                              void* d_out, int out_size, void* d_ws, size_t ws_size,
                              hipStream_t stream) {
  const float* x = (const float*)d_in[0];
  const int* ei = (const int*)d_in[1];
  const float* cW1 = (const float*)d_in[2];
  const float* cb1 = (const float*)d_in[5];
  const float* cW3 = (const float*)d_in[6];
  const float* cb3 = (const float*)d_in[9];
  const float* e1W1 = (const float*)d_in[10];
  const float* e1b1 = (const float*)d_in[11];
  const float* e1W2 = (const float*)d_in[12];
  const float* e1b2 = (const float*)d_in[13];
  const float* e2W1 = (const float*)d_in[14];
  const float* e2b1 = (const float*)d_in[15];
  const float* e2W2 = (const float*)d_in[16];
  const float* e2b2 = (const float*)d_in[17];
  const float* l1W = (const float*)d_in[18];
  const float* l1b = (const float*)d_in[19];
  const float* l2W = (const float*)d_in[20];
  const float* l2b = (const float*)d_in[21];
  const float* l3W = (const float*)d_in[22];
  const float* l3b = (const float*)d_in[23];
  const float* oW = (const float*)d_in[24];
  const float* ob = (const float*)d_in[25];
  float* out = (float*)d_out;

  // workspace layout
  char* p = (char*)d_ws;
  auto alloc = [&](size_t bytes) {
    char* r = p;
    p += (bytes + 255) & ~(size_t)255;
    return r;
  };
  float* x1 = (float*)alloc((size_t)Nn * 16 * 4);
  float* y1 = (float*)alloc((size_t)Nn * 32 * 4);
  float* y2 = (float*)alloc((size_t)Nn * 32 * 4);
  float* x3 = (float*)alloc((size_t)Nn * 64 * 4);
  float* agg = (float*)alloc((size_t)Nn * 48 * 4);
  int* cnt = (int*)alloc((size_t)Nn * 4);
  float* sqb = (float*)alloc((size_t)Nn * 4);
  int* idx1 = (int*)alloc((size_t)Nn * KN * 4);
  int* idx2 = (int*)alloc((size_t)Nn * KN * 4);
  size_t fixed_bytes = (size_t)(p - (char*)d_ws);
  size_t per_chunk = (size_t)Nn * KN * 4 * 2 + 512;  // pd + pi (+padding)
  int P = 32;  // was 16: 640 blocks -> ~5 waves/CU, latency-bound (VALUBusy 35%)
  if (fixed_bytes + (size_t)P * per_chunk > ws_size) {
    size_t avail = ws_size > fixed_bytes ? ws_size - fixed_bytes : 0;
    int pmax = (int)(avail / per_chunk);
    P = pmax < 1 ? 1 : pmax;
    if (P > 32) P = 32;
  }
  float* pd = (float*)alloc((size_t)P * Nn * KN * 4);
  int* pi = (int*)alloc((size_t)P * Nn * KN * 4);
  int chunk = (Nn + P - 1) / P;

  // ---- feast1 ----
  hipMemsetAsync(agg, 0, (size_t)Nn * 16 * 4, stream);
  hipMemsetAsync(cnt, 0, (size_t)Nn * 4, stream);
  scatter16<<<(Ee * 16) / 256, 256, 0, stream>>>(x, ei, agg, cnt);
  feast1_fin<<<(Nn + 255) / 256, 256, 0, stream>>>(x, agg, cnt, cW1, cb1, x1, sqb);

  // ---- kNN 1 (C=16, R=2: 79*P blocks for occupancy) ----
  {
    dim3 grid((Nn + 128 * 2 - 1) / (128 * 2), P);
    knn_part<16, 2, 128><<<grid, 128, 0, stream>>>(x1, sqb, pd, pi, chunk);
    knn_merge<<<(Nn + 255) / 256, 256, 0, stream>>>(pd, pi, idx1, P);
  }

  // ---- edge conv 1 ----
  edge_mlp1<<<(Nn + 7) / 8, 256, 0, stream>>>(x1, idx1, e1W1, e1b1, e1W2, e1b2, y1, sqb);

  // ---- kNN 2 (C=32, R=1: 157*P blocks) ----
  {
    dim3 grid((Nn + 128 - 1) / 128, P);
    knn_part<32, 1, 128><<<grid, 128, 0, stream>>>(y1, sqb, pd, pi, chunk);
    knn_merge<<<(Nn + 255) / 256, 256, 0, stream>>>(pd, pi, idx2, P);
  }

  // ---- edge conv 2 ----
  edge_mlp2<<<(Nn + 7) / 8, 256, 0, stream>>>(y1, idx2, e2W1, e2b1, e2W2, e2b2, y2);

  // ---- feast3 (cat0 = [x1, y1]) ----
  hipMemsetAsync(agg, 0, (size_t)Nn * 48 * 4, stream);
  scatter48<<<(Ee * 48) / 256, 256, 0, stream>>>(x1, y1, ei, agg);
  feast3_fin<<<(Nn + 255) / 256, 256, 0, stream>>>(x1, y1, agg, cnt, cW3, cb3, x3);

  // ---- final MLP ----
  final_mlp<<<(Nn + 1) / 2, 256, 0, stream>>>(x3, y2, l1W, l1b, l2W, l2b, l3W, l3b,
                                              oW, ob, out);
}

// Round 2
// 1480.124 us; speedup vs baseline: 1.4266x; 1.0772x over previous
//
#include <hip/hip_runtime.h>
#include <cstdint>

constexpr int Nn = 20000;
constexpr int Ee = 320000;   // Nn * 16
constexpr int KN = 6;

// ---------------------------------------------------------------------------
// feast1: scatter-add x[src] into agg16[dst], count in-degree
// ---------------------------------------------------------------------------
__global__ __launch_bounds__(256) void scatter16(const float* __restrict__ x,
                                                 const int* __restrict__ ei,
                                                 float* __restrict__ agg,
                                                 int* __restrict__ cnt) {
  int tid = blockIdx.x * 256 + threadIdx.x;
  int e = tid >> 4, c = tid & 15;
  if (e >= Ee) return;
  int s = ei[e], d = ei[Ee + e];
  unsafeAtomicAdd(&agg[d * 16 + c], x[s * 16 + c]);
  if (c == 0) atomicAdd(&cnt[d], 1);
}

// feast1 finalize: x1 = relu(((agg + x)/ (cnt+1)) @ cW1 + cb1); sq = ||x1||^2
__global__ __launch_bounds__(256) void feast1_fin(const float* __restrict__ x,
                                                  const float* __restrict__ agg,
                                                  const int* __restrict__ cnt,
                                                  const float* __restrict__ W,
                                                  const float* __restrict__ b,
                                                  float* __restrict__ x1,
                                                  float* __restrict__ sq) {
  __shared__ float sW[256];
  __shared__ float sb[16];
  sW[threadIdx.x] = W[threadIdx.x];
  if (threadIdx.x < 16) sb[threadIdx.x] = b[threadIdx.x];
  __syncthreads();
  int n = blockIdx.x * 256 + threadIdx.x;
  if (n >= Nn) return;
  float inv = 1.0f / (float)(cnt[n] + 1);
  float v[16];
#pragma unroll
  for (int c = 0; c < 16; ++c) v[c] = (agg[n * 16 + c] + x[n * 16 + c]) * inv;
  float s = 0.0f;
#pragma unroll
  for (int o = 0; o < 16; ++o) {
    float a = sb[o];
#pragma unroll
    for (int c = 0; c < 16; ++c) a = fmaf(v[c], sW[c * 16 + o], a);
    a = fmaxf(a, 0.0f);
    x1[n * 16 + o] = a;
    s = fmaf(a, a, s);
  }
  sq[n] = s;
}

// ---------------------------------------------------------------------------
// kNN: partial top-6 per (row, column-chunk). xj loaded with wave-uniform j
// (scalar loads, SGPR-broadcast FMA). R=1 row per thread: keeps the wave-level
// insertion-branch body small (one insertion sort, not two) and L=64 rows/wave
// halves the top-6 "fill" constant vs R=2. Chunk length chosen so the fill
// phase (~384 always-insert iterations per wave) amortizes: slow-path rate
// ~60% instead of ~100% at chunk=625.
// Selection key: ||xj||^2 - 2 xi.xj  (row-constant ||xi||^2 dropped).
// ---------------------------------------------------------------------------
__device__ __forceinline__ void insert6(float d, int j, float (&bd)[KN], int (&bi)[KN]) {
  bd[KN - 1] = d;
  bi[KN - 1] = j;
#pragma unroll
  for (int k = KN - 1; k >= 1; --k) {
    if (bd[k] < bd[k - 1]) {
      float td = bd[k]; bd[k] = bd[k - 1]; bd[k - 1] = td;
      int ti = bi[k]; bi[k] = bi[k - 1]; bi[k - 1] = ti;
    }
  }
}

template <int C, int U, int TPB>
__global__ __launch_bounds__(TPB) void knn_part(const float* __restrict__ xf,
                                                const float* __restrict__ sq,
                                                float* __restrict__ pd,
                                                int* __restrict__ pi, int chunk) {
  const int row = blockIdx.x * TPB + (int)threadIdx.x;
  const int p = blockIdx.y;
  const int j0 = p * chunk;
  int j1 = j0 + chunk;
  if (j1 > Nn) j1 = Nn;

  float xi[C];
  {
    const float* src = xf + (size_t)(row < Nn ? row : 0) * C;
#pragma unroll
    for (int c = 0; c < C; ++c) xi[c] = src[c];
  }
  float bd[KN];
  int bi[KN];
#pragma unroll
  for (int k = 0; k < KN; ++k) { bd[k] = __builtin_inff(); bi[k] = -1; }

  int j = j0;
  // main loop: U candidates per iteration; dot products issue back-to-back,
  // gates afterwards so the FMA stream stays dense between branch clusters.
  for (; j + U <= j1; j += U) {
    float sv[U];
#pragma unroll
    for (int u = 0; u < U; ++u) {
      const float* xjp = xf + (size_t)(j + u) * C;  // uniform addr -> s_load
      float sqj = sq[j + u];
      float acc = 0.0f;
#pragma unroll
      for (int c = 0; c < C; ++c) acc = fmaf(xi[c], xjp[c], acc);
      float d = fmaf(-2.0f, acc, sqj);
      sv[u] = (j + u == row) ? __builtin_inff() : d;
    }
#pragma unroll
    for (int u = 0; u < U; ++u) {
      if (sv[u] < bd[KN - 1]) insert6(sv[u], j + u, bd, bi);
    }
  }
  // tail
  for (; j < j1; ++j) {
    const float* xjp = xf + (size_t)j * C;
    float sqj = sq[j];
    float acc = 0.0f;
#pragma unroll
    for (int c = 0; c < C; ++c) acc = fmaf(xi[c], xjp[c], acc);
    float d = fmaf(-2.0f, acc, sqj);
    d = (j == row) ? __builtin_inff() : d;
    if (d < bd[KN - 1]) insert6(d, j, bd, bi);
  }

  if (row < Nn) {
    size_t base = ((size_t)p * Nn + row) * KN;
    for (int k = 0; k < KN; ++k) { pd[base + k] = bd[k]; pi[base + k] = bi[k]; }
  }
}

// merge P partial top-6 lists (stable: ascending p == ascending j ranges)
__global__ __launch_bounds__(256) void knn_merge(const float* __restrict__ pd,
                                                 const int* __restrict__ pi,
                                                 int* __restrict__ idx, int P) {
  int row = blockIdx.x * 256 + threadIdx.x;
  if (row >= Nn) return;
  float bd[KN];
  int bi[KN];
#pragma unroll
  for (int k = 0; k < KN; ++k) { bd[k] = __builtin_inff(); bi[k] = -1; }
  for (int p = 0; p < P; ++p) {
    size_t base = ((size_t)p * Nn + row) * KN;
#pragma unroll
    for (int k = 0; k < KN; ++k) {
      float d = pd[base + k];
      int id = pi[base + k];
      if (d < bd[KN - 1]) {
        bd[KN - 1] = d; bi[KN - 1] = id;
#pragma unroll
        for (int m = KN - 1; m >= 1; --m) {
          if (bd[m] < bd[m - 1]) {
            float td = bd[m]; bd[m] = bd[m - 1]; bd[m - 1] = td;
            int ti = bi[m]; bi[m] = bi[m - 1]; bi[m - 1] = ti;
          }
        }
      }
    }
  }
  for (int k = 0; k < KN; ++k) idx[row * KN + k] = bi[k];
}

// ---------------------------------------------------------------------------
// EdgeConv MLP 1: in 16 -> tmp 32 -> hidden 32 -> out 32, max over 6 nbrs,
// y1 = relu(max), also sq2 = ||y1||^2. 8 nodes/block, 32 threads/node.
// ---------------------------------------------------------------------------
__global__ __launch_bounds__(256) void edge_mlp1(const float* __restrict__ xin,
                                                 const int* __restrict__ idx,
                                                 const float* __restrict__ W1,
                                                 const float* __restrict__ b1,
                                                 const float* __restrict__ W2,
                                                 const float* __restrict__ b2,
                                                 float* __restrict__ yout,
                                                 float* __restrict__ sqout) {
  __shared__ float sW1[1024], sW2[1024], sb1[32], sb2[32];
  __shared__ float xv[8][16], tmp[8][32], hv[8][32];
  int t = threadIdx.x & 31, g = threadIdx.x >> 5;
  for (int i = threadIdx.x; i < 1024; i += 256) { sW1[i] = W1[i]; sW2[i] = W2[i]; }
  if (threadIdx.x < 32) { sb1[threadIdx.x] = b1[threadIdx.x]; sb2[threadIdx.x] = b2[threadIdx.x]; }
  int node = blockIdx.x * 8 + g;
  bool valid = node < Nn;
  int nn = valid ? node : 0;
  if (t < 16) { float v = xin[nn * 16 + t]; xv[g][t] = v; tmp[g][t] = v; }
  __syncthreads();
  float acc = -__builtin_inff();
  for (int k = 0; k < KN; ++k) {
    int j = idx[nn * KN + k];
    if (t < 16) tmp[g][16 + t] = xin[j * 16 + t] - xv[g][t];
    __syncthreads();
    float h = sb1[t];
#pragma unroll
    for (int c = 0; c < 32; ++c) h = fmaf(tmp[g][c], sW1[c * 32 + t], h);
    h = fmaxf(h, 0.0f);
    hv[g][t] = h;
    __syncthreads();
    float o = sb2[t];
#pragma unroll
    for (int c = 0; c < 32; ++c) o = fmaf(hv[g][c], sW2[c * 32 + t], o);
    acc = fmaxf(acc, o);
  }
  float yv = fmaxf(acc, 0.0f);
  if (valid) yout[node * 32 + t] = yv;
  float s = yv * yv;
  s += __shfl_xor(s, 16, 32);
  s += __shfl_xor(s, 8, 32);
  s += __shfl_xor(s, 4, 32);
  s += __shfl_xor(s, 2, 32);
  s += __shfl_xor(s, 1, 32);
  if (valid && t == 0) sqout[node] = s;
}

// EdgeConv MLP 2: in 32 -> tmp 64 -> hidden 32 -> out 32, y2 = relu(max)
__global__ __launch_bounds__(256) void edge_mlp2(const float* __restrict__ yin,
                                                 const int* __restrict__ idx,
                                                 const float* __restrict__ W1,
                                                 const float* __restrict__ b1,
                                                 const float* __restrict__ W2,
                                                 const float* __restrict__ b2,
                                                 float* __restrict__ yout) {
  __shared__ float sW1[2048], sW2[1024], sb1[32], sb2[32];
  __shared__ float xv[8][32], tmp[8][64], hv[8][32];
  int t = threadIdx.x & 31, g = threadIdx.x >> 5;
  for (int i = threadIdx.x; i < 2048; i += 256) sW1[i] = W1[i];
  for (int i = threadIdx.x; i < 1024; i += 256) sW2[i] = W2[i];
  if (threadIdx.x < 32) { sb1[threadIdx.x] = b1[threadIdx.x]; sb2[threadIdx.x] = b2[threadIdx.x]; }
  int node = blockIdx.x * 8 + g;
  bool valid = node < Nn;
  int nn = valid ? node : 0;
  { float v = yin[nn * 32 + t]; xv[g][t] = v; tmp[g][t] = v; }
  __syncthreads();
  float acc = -__builtin_inff();
  for (int k = 0; k < KN; ++k) {
    int j = idx[nn * KN + k];
    tmp[g][32 + t] = yin[j * 32 + t] - xv[g][t];
    __syncthreads();
    float h = sb1[t];
#pragma unroll
    for (int c = 0; c < 64; ++c) h = fmaf(tmp[g][c], sW1[c * 32 + t], h);
    h = fmaxf(h, 0.0f);
    hv[g][t] = h;
    __syncthreads();
    float o = sb2[t];
#pragma unroll
    for (int c = 0; c < 32; ++c) o = fmaf(hv[g][c], sW2[c * 32 + t], o);
    acc = fmaxf(acc, o);
  }
  if (valid) yout[node * 32 + t] = fmaxf(acc, 0.0f);
}

// ---------------------------------------------------------------------------
// feast3: scatter cat0 = [x1, y1] (48) into agg48[dst]; reuse cnt from feast1
// ---------------------------------------------------------------------------
__global__ __launch_bounds__(256) void scatter48(const float* __restrict__ x1,
                                                 const float* __restrict__ y1,
                                                 const int* __restrict__ ei,
                                                 float* __restrict__ agg) {
  int tid = blockIdx.x * 256 + threadIdx.x;
  int e = tid / 48, c = tid - e * 48;
  if (e >= Ee) return;
  int s = ei[e], d = ei[Ee + e];
  float v = (c < 16) ? x1[s * 16 + c] : y1[s * 32 + (c - 16)];
  unsafeAtomicAdd(&agg[d * 48 + c], v);
}

// feast3 finalize: x3 = relu(((agg48 + cat0)/(cnt+1)) @ cW3 + cb3)
__global__ __launch_bounds__(256) void feast3_fin(const float* __restrict__ x1,
                                                  const float* __restrict__ y1,
                                                  const float* __restrict__ agg,
                                                  const int* __restrict__ cnt,
                                                  const float* __restrict__ W,
                                                  const float* __restrict__ b,
                                                  float* __restrict__ x3) {
  __shared__ float sW[3072];
  __shared__ float sb[64];
  for (int i = threadIdx.x; i < 3072; i += 256) sW[i] = W[i];
  if (threadIdx.x < 64) sb[threadIdx.x] = b[threadIdx.x];
  __syncthreads();
  int n = blockIdx.x * 256 + threadIdx.x;
  if (n >= Nn) return;
  float inv = 1.0f / (float)(cnt[n] + 1);
  float v[48];
#pragma unroll
  for (int c = 0; c < 16; ++c) v[c] = (agg[n * 48 + c] + x1[n * 16 + c]) * inv;
#pragma unroll
  for (int c = 16; c < 48; ++c) v[c] = (agg[n * 48 + c] + y1[n * 32 + (c - 16)]) * inv;
  for (int o = 0; o < 64; ++o) {
    float a = sb[o];
#pragma unroll
    for (int c = 0; c < 48; ++c) a = fmaf(v[c], sW[c * 64 + o], a);
    x3[n * 64 + o] = fmaxf(a, 0.0f);
  }
}

// ---------------------------------------------------------------------------
// Fused final MLP: cat1=[x3,y2](96) -> 96 -> 32 -> 8 -> sigmoid(1)
// 2 nodes/block, 128 threads/node; weights stream from L1/L2.
// ---------------------------------------------------------------------------
__global__ __launch_bounds__(256) void final_mlp(const float* __restrict__ x3,
                                                 const float* __restrict__ y2,
                                                 const float* __restrict__ l1W,
                                                 const float* __restrict__ l1b,
                                                 const float* __restrict__ l2W,
                                                 const float* __restrict__ l2b,
                                                 const float* __restrict__ l3W,
                                                 const float* __restrict__ l3b,
                                                 const float* __restrict__ oW,
                                                 const float* __restrict__ ob,
                                                 float* __restrict__ out) {
  __shared__ float cat[2][96], h1[2][96], h2[2][32], h3[2][8];
  int g = threadIdx.x >> 7, t = threadIdx.x & 127;
  int node = blockIdx.x * 2 + g;
  bool valid = node < Nn;
  int nn = valid ? node : 0;
  if (t < 96) cat[g][t] = (t < 64) ? x3[nn * 64 + t] : y2[nn * 32 + (t - 64)];
  __syncthreads();
  if (t < 96) {
    float a = l1b[t];
#pragma unroll
    for (int c = 0; c < 96; ++c) a = fmaf(cat[g][c], l1W[c * 96 + t], a);
    h1[g][t] = fmaxf(a, 0.0f);
  }
  __syncthreads();
  if (t < 32) {
    float a = l2b[t];
#pragma unroll
    for (int c = 0; c < 96; ++c) a = fmaf(h1[g][c], l2W[c * 32 + t], a);
    h2[g][t] = fmaxf(a, 0.0f);
  }
  __syncthreads();
  if (t < 8) {
    float a = l3b[t];
#pragma unroll
    for (int c = 0; c < 32; ++c) a = fmaf(h2[g][c], l3W[c * 8 + t], a);
    h3[g][t] = fmaxf(a, 0.0f);
  }
  __syncthreads();
  if (t == 0 && valid) {
    float a = ob[0];
#pragma unroll
    for (int c = 0; c < 8; ++c) a = fmaf(h3[g][c], oW[c], a);
    out[node] = 1.0f / (1.0f + expf(-a));
  }
}

// ---------------------------------------------------------------------------
extern "C" void kernel_launch(void* const* d_in, const int* in_sizes, int n_in,
                              void* d_out, int out_size, void* d_ws, size_t ws_size,
                              hipStream_t stream) {
  const float* x = (const float*)d_in[0];
  const int* ei = (const int*)d_in[1];
  const float* cW1 = (const float*)d_in[2];
  const float* cb1 = (const float*)d_in[5];
  const float* cW3 = (const float*)d_in[6];
  const float* cb3 = (const float*)d_in[9];
  const float* e1W1 = (const float*)d_in[10];
  const float* e1b1 = (const float*)d_in[11];
  const float* e1W2 = (const float*)d_in[12];
  const float* e1b2 = (const float*)d_in[13];
  const float* e2W1 = (const float*)d_in[14];
  const float* e2b1 = (const float*)d_in[15];
  const float* e2W2 = (const float*)d_in[16];
  const float* e2b2 = (const float*)d_in[17];
  const float* l1W = (const float*)d_in[18];
  const float* l1b = (const float*)d_in[19];
  const float* l2W = (const float*)d_in[20];
  const float* l2b = (const float*)d_in[21];
  const float* l3W = (const float*)d_in[22];
  const float* l3b = (const float*)d_in[23];
  const float* oW = (const float*)d_in[24];
  const float* ob = (const float*)d_in[25];
  float* out = (float*)d_out;

  // workspace layout
  char* p = (char*)d_ws;
  auto alloc = [&](size_t bytes) {
    char* r = p;
    p += (bytes + 255) & ~(size_t)255;
    return r;
  };
  float* x1 = (float*)alloc((size_t)Nn * 16 * 4);
  float* y1 = (float*)alloc((size_t)Nn * 32 * 4);
  float* y2 = (float*)alloc((size_t)Nn * 32 * 4);
  float* x3 = (float*)alloc((size_t)Nn * 64 * 4);
  float* agg = (float*)alloc((size_t)Nn * 48 * 4);
  int* cnt = (int*)alloc((size_t)Nn * 4);
  float* sqb = (float*)alloc((size_t)Nn * 4);
  int* idx1 = (int*)alloc((size_t)Nn * KN * 4);
  int* idx2 = (int*)alloc((size_t)Nn * KN * 4);
  size_t fixed_bytes = (size_t)(p - (char*)d_ws);
  size_t per_chunk = (size_t)Nn * KN * 4 * 2 + 512;  // pd + pi (+padding)
  int P1 = 16;   // kNN1 chunks: chunk=1250, slow-path ~67% instead of 100%
  int P2 = 12;   // kNN2 chunks: chunk=1667, slow-path ~57%, 3.7 waves/SIMD
  if (fixed_bytes + (size_t)P1 * per_chunk > ws_size) {
    size_t avail = ws_size > fixed_bytes ? ws_size - fixed_bytes : 0;
    int pmax = (int)(avail / per_chunk);
    P1 = pmax < 1 ? 1 : pmax;
    if (P1 > 16) P1 = 16;
    if (P2 > P1) P2 = P1;
  }
  float* pd = (float*)alloc((size_t)P1 * Nn * KN * 4);
  int* pi = (int*)alloc((size_t)P1 * Nn * KN * 4);
  int chunk1 = (Nn + P1 - 1) / P1;
  int chunk2 = (Nn + P2 - 1) / P2;

  // ---- feast1 ----
  hipMemsetAsync(agg, 0, (size_t)Nn * 16 * 4, stream);
  hipMemsetAsync(cnt, 0, (size_t)Nn * 4, stream);
  scatter16<<<(Ee * 16) / 256, 256, 0, stream>>>(x, ei, agg, cnt);
  feast1_fin<<<(Nn + 255) / 256, 256, 0, stream>>>(x, agg, cnt, cW1, cb1, x1, sqb);

  // ---- kNN 1 (C=16, R=1, U=4) ----
  {
    dim3 grid((Nn + 255) / 256, P1);
    knn_part<16, 4, 256><<<grid, 256, 0, stream>>>(x1, sqb, pd, pi, chunk1);
    knn_merge<<<(Nn + 255) / 256, 256, 0, stream>>>(pd, pi, idx1, P1);
  }

  // ---- edge conv 1 ----
  edge_mlp1<<<(Nn + 7) / 8, 256, 0, stream>>>(x1, idx1, e1W1, e1b1, e1W2, e1b2, y1, sqb);

  // ---- kNN 2 (C=32, R=1, U=2) ----
  {
    dim3 grid((Nn + 255) / 256, P2);
    knn_part<32, 2, 256><<<grid, 256, 0, stream>>>(y1, sqb, pd, pi, chunk2);
    knn_merge<<<(Nn + 255) / 256, 256, 0, stream>>>(pd, pi, idx2, P2);
  }

  // ---- edge conv 2 ----
  edge_mlp2<<<(Nn + 7) / 8, 256, 0, stream>>>(y1, idx2, e2W1, e2b1, e2W2, e2b2, y2);

  // ---- feast3 (cat0 = [x1, y1]) ----
  hipMemsetAsync(agg, 0, (size_t)Nn * 48 * 4, stream);
  scatter48<<<(Ee * 48) / 256, 256, 0, stream>>>(x1, y1, ei, agg);
  feast3_fin<<<(Nn + 255) / 256, 256, 0, stream>>>(x1, y1, agg, cnt, cW3, cb3, x3);

  // ---- final MLP ----
  final_mlp<<<(Nn + 1) / 2, 256, 0, stream>>>(x3, y2, l1W, l1b, l2W, l2b, l3W, l3b,
                                              oW, ob, out);
}